// Round 1
// baseline (938.900 us; speedup 1.0000x reference)
//
#include <hip/hip_runtime.h>
#include <hip/hip_bf16.h>
#include <math.h>

// MoE FFN: N=8192 tokens, C=1024, H=4096, E=8, TOP_K=2.
// Round 3: 2-phase double-buffered K-loop (STAGE(t+1) overlaps MFMA(t),
// ONE barrier per K-step instead of two with exposed load latency);
// bijective XCD-aware block swizzle (m204); cvt kernels fused into one;
// prefix_k folded into fc1/fc2 (offs computed from counts per-block).
//   router (fp32) -> per-expert compacted token lists
//   fc1: h = gelu(x_gathered @ w1^T)   [bf16 MFMA, fp32 acc]
//   fc2: out += gate * (h @ w2^T)      [atomicAdd fp32 scatter]

#define N_TOK   8192
#define C_DIM   1024
#define H_DIM   4096
#define N_EXP   8
#define CAP     8192   // per-expert worst-case capacity

typedef __bf16 bf16;
typedef bf16  bf16x8 __attribute__((ext_vector_type(8)));
typedef float f32x4  __attribute__((ext_vector_type(4)));

__device__ __forceinline__ void async_ld16(const void* g, void* l) {
    __builtin_amdgcn_global_load_lds(
        (const __attribute__((address_space(1))) void*)g,
        (__attribute__((address_space(3))) void*)l,
        16, 0, 0);
}

__device__ __forceinline__ float gelu_f(float v) {
    float u = v + 0.044715f * v * v * v;
    return 0.5f * v * (1.0f + tanhf(0.7978845608028654f * u));
}

// ---------------- fp32 -> bf16 for x, w1, w2 in one launch ----------------
#define NX8 ((size_t)N_TOK * C_DIM / 8)                 // 1,048,576
#define NW8 ((size_t)N_EXP * H_DIM * C_DIM / 8)        // 4,194,304
#define NCVT (NX8 + 2 * NW8)                            // 9,437,184 -> 36864 blocks

__global__ __launch_bounds__(256) void cvt_all_k(const float* __restrict__ x,
                                                 const float* __restrict__ w1,
                                                 const float* __restrict__ w2,
                                                 bf16* __restrict__ xb,
                                                 bf16* __restrict__ w1b,
                                                 bf16* __restrict__ w2b) {
    size_t i = (size_t)blockIdx.x * 256 + threadIdx.x;
    if (i >= NCVT) return;
    const float* src; bf16* dst; size_t j;
    if (i < NX8)            { src = x;  dst = xb;  j = i; }
    else if (i < NX8 + NW8) { src = w1; dst = w1b; j = i - NX8; }
    else                    { src = w2; dst = w2b; j = i - NX8 - NW8; }
    const float4* p = (const float4*)src + j * 2;
    float4 a = p[0], b = p[1];
    bf16x8 v;
    v[0] = (bf16)a.x; v[1] = (bf16)a.y; v[2] = (bf16)a.z; v[3] = (bf16)a.w;
    v[4] = (bf16)b.x; v[5] = (bf16)b.y; v[6] = (bf16)b.z; v[7] = (bf16)b.w;
    *((bf16x8*)dst + j) = v;
}

// ---------------- router: logits -> softmax -> top2 -> compacted lists ----------------
__global__ __launch_bounds__(1024) void router_k(const float* __restrict__ x,
                                                 const float* __restrict__ rw,
                                                 int* __restrict__ counts,
                                                 int* __restrict__ tok,
                                                 float* __restrict__ gate) {
    __shared__ int lcnt[N_EXP];
    __shared__ int lbase[N_EXP];
    const int tid  = threadIdx.x;
    const int lane = tid & 63;
    const int wv   = tid >> 6;          // 16 waves -> 16 tokens per block
    if (tid < N_EXP) lcnt[tid] = 0;
    __syncthreads();

    const int t = blockIdx.x * 16 + wv;

    float dot[N_EXP];
#pragma unroll
    for (int e = 0; e < N_EXP; ++e) dot[e] = 0.f;
    const float4* xr = (const float4*)(x + (size_t)t * C_DIM);
#pragma unroll
    for (int j = 0; j < 4; ++j) {
        float4 xv = xr[j * 64 + lane];
#pragma unroll
        for (int e = 0; e < N_EXP; ++e) {
            float4 w4 = ((const float4*)(rw + (size_t)e * C_DIM))[j * 64 + lane];
            dot[e] += xv.x * w4.x + xv.y * w4.y + xv.z * w4.z + xv.w * w4.w;
        }
    }
#pragma unroll
    for (int e = 0; e < N_EXP; ++e) {
#pragma unroll
        for (int o = 32; o > 0; o >>= 1) dot[e] += __shfl_xor(dot[e], o, 64);
    }

    int a = 0, b = 0, ra = 0, rb = 0;
    float g0 = 0.f, g1 = 0.f;
    if (lane == 0) {
        float m = dot[0];
#pragma unroll
        for (int e = 1; e < N_EXP; ++e) m = fmaxf(m, dot[e]);
        float p[N_EXP]; float s = 0.f;
#pragma unroll
        for (int e = 0; e < N_EXP; ++e) { p[e] = expf(dot[e] - m); s += p[e]; }
        a = 0;
#pragma unroll
        for (int e = 1; e < N_EXP; ++e) if (p[e] > p[a]) a = e;
        b = -1;
#pragma unroll
        for (int e = 0; e < N_EXP; ++e) if (e != a && (b < 0 || p[e] > p[b])) b = e;
        float pa = p[a] / s, pb = p[b] / s;
        float d = pa + pb + 1e-8f;
        g0 = pa / d; g1 = pb / d;
        ra = atomicAdd(&lcnt[a], 1);
        rb = atomicAdd(&lcnt[b], 1);
    }
    __syncthreads();
    if (tid < N_EXP) lbase[tid] = atomicAdd(&counts[tid], lcnt[tid]);
    __syncthreads();
    if (lane == 0) {
        int sa = lbase[a] + ra;
        int sb = lbase[b] + rb;
        tok[a * CAP + sa] = t;  gate[a * CAP + sa] = g0;
        tok[b * CAP + sb] = t;  gate[b * CAP + sb] = g1;
    }
}

// XOR swizzle: LDS chunk (row, c) holds global 8-elem group (row, c ^ s(row)),
// s(row) = (row>>1)&3.  Staging lane l (within a 16-row block): row = l>>2,
// c = l&3  => global col group = (l&3) ^ ((l>>3)&3).
// Fragment read (m-row r = lane&15, k-group g = lane>>4): chunk c = g ^ ((r>>1)&3).
// => each group of 8 consecutive lanes of a ds_read_b128 covers all 32 banks once.

// ---------------- fc1: h = gelu(x_gathered @ w1^T + b1) ----------------
__global__ __launch_bounds__(256) void fc1_k(const bf16* __restrict__ xb,
                                             const bf16* __restrict__ w1b,
                                             const float* __restrict__ b1,
                                             const int* __restrict__ counts,
                                             const int* __restrict__ tok,
                                             bf16* __restrict__ h) {
    // Bijective XCD swizzle (m204): nwg = 32*64*8 = 16384, q = 2048, nwg%8==0.
    const int lin = blockIdx.x + 32 * (blockIdx.y + 64 * blockIdx.z);
    const int w   = (lin & 7) * 2048 + (lin >> 3);
    const int e   = w >> 11;          // / (32*64)
    const int by  = (w >> 5) & 63;
    const int bx  = w & 31;

    const int cnt = counts[e];
    const int m0  = by * 128;
    if (m0 >= cnt) return;
    const int n0  = bx * 128;

    int off = 0;
    for (int j = 0; j < e; ++j) off += counts[j];   // inline prefix (uniform scalar loads)

    __shared__ __align__(16) bf16 As[2][128][32];
    __shared__ __align__(16) bf16 Bs[2][128][32];

    const int tid  = threadIdx.x;
    const int lane = tid & 63;
    const int wv   = tid >> 6;
    const int wm   = wv & 1;
    const int wn   = wv >> 1;

    // swizzled source column (elements) for staging
    const int scol = (((lane & 3) ^ ((lane >> 3) & 3))) * 8;

    const int ar0 = wv * 16 + (lane >> 2);
    const int ar1 = 64 + ar0;
    const int i0 = m0 + ar0, i1 = m0 + ar1;
    const int t0 = tok[e * CAP + (i0 < cnt ? i0 : cnt - 1)];
    const int t1 = tok[e * CAP + (i1 < cnt ? i1 : cnt - 1)];
    const bf16* ga0 = xb + (size_t)t0 * C_DIM + scol;
    const bf16* ga1 = xb + (size_t)t1 * C_DIM + scol;
    const bf16* gb0 = w1b + ((size_t)e * H_DIM + n0 + ar0) * C_DIM + scol;
    const bf16* gb1 = w1b + ((size_t)e * H_DIM + n0 + ar1) * C_DIM + scol;

    f32x4 acc[4][4];
#pragma unroll
    for (int mi = 0; mi < 4; ++mi)
#pragma unroll
        for (int ni = 0; ni < 4; ++ni)
#pragma unroll
            for (int r = 0; r < 4; ++r) acc[mi][ni][r] = 0.f;

    const int r_   = lane & 15;
    const int g_   = lane >> 4;
    const int rcol = (g_ ^ ((r_ >> 1) & 3)) * 8;   // swizzled read column

#define STAGE1(b, kt) do { const int k0_ = (kt) * 32;        \
    async_ld16(ga0 + k0_, &As[b][wv * 16][0]);               \
    async_ld16(ga1 + k0_, &As[b][64 + wv * 16][0]);          \
    async_ld16(gb0 + k0_, &Bs[b][wv * 16][0]);               \
    async_ld16(gb1 + k0_, &Bs[b][64 + wv * 16][0]); } while (0)

    STAGE1(0, 0);
    __syncthreads();                 // drains vmcnt(0): buf0 ready
    int cur = 0;
    for (int kt = 0; kt < C_DIM / 32; ++kt) {
        if (kt + 1 < C_DIM / 32) STAGE1(cur ^ 1, kt + 1);   // prefetch overlaps MFMA

        bf16x8 af[4];
#pragma unroll
        for (int mi = 0; mi < 4; ++mi)
            af[mi] = *(const bf16x8*)&As[cur][wm * 64 + mi * 16 + r_][rcol];
#pragma unroll
        for (int ni = 0; ni < 4; ++ni) {
            bf16x8 bfr = *(const bf16x8*)&Bs[cur][wn * 64 + ni * 16 + r_][rcol];
#pragma unroll
            for (int mi = 0; mi < 4; ++mi)
                acc[mi][ni] = __builtin_amdgcn_mfma_f32_16x16x32_bf16(af[mi], bfr, acc[mi][ni], 0, 0, 0);
        }
        __syncthreads();             // drains vmcnt(0): prefetch landed; reads done
        cur ^= 1;
    }
#undef STAGE1

    const int lg = lane >> 4, ln = lane & 15;
#pragma unroll
    for (int mi = 0; mi < 4; ++mi) {
#pragma unroll
        for (int r = 0; r < 4; ++r) {
            const int m = wm * 64 + mi * 16 + lg * 4 + r;
            if (m0 + m < cnt) {
                const size_t hrow = (size_t)(off + m0 + m) * H_DIM;
#pragma unroll
                for (int ni = 0; ni < 4; ++ni) {
                    const int n = n0 + wn * 64 + ni * 16 + ln;
                    float v = acc[mi][ni][r] + b1[(size_t)e * H_DIM + n];
                    h[hrow + n] = (bf16)gelu_f(v);
                }
            }
        }
    }
}

// ---------------- fc2: out += gate * (h @ w2^T + b2) ----------------
__global__ __launch_bounds__(256) void fc2_k(const bf16* __restrict__ h,
                                             const bf16* __restrict__ w2b,
                                             const float* __restrict__ b2,
                                             const int* __restrict__ counts,
                                             const int* __restrict__ tok,
                                             const float* __restrict__ gate,
                                             float* __restrict__ out) {
    // Bijective XCD swizzle (m204): nwg = 8*64*8 = 4096, q = 512, nwg%8==0.
    const int lin = blockIdx.x + 8 * (blockIdx.y + 64 * blockIdx.z);
    const int w   = (lin & 7) * 512 + (lin >> 3);
    const int e   = w >> 9;           // / (8*64)
    const int by  = (w >> 3) & 63;
    const int bx  = w & 7;

    const int cnt = counts[e];
    const int m0  = by * 128;
    if (m0 >= cnt) return;
    const int n0  = bx * 128;

    int off = 0;
    for (int j = 0; j < e; ++j) off += counts[j];

    __shared__ __align__(16) bf16 As[2][128][32];
    __shared__ __align__(16) bf16 Bs[2][128][32];

    const int tid  = threadIdx.x;
    const int lane = tid & 63;
    const int wv   = tid >> 6;
    const int wm   = wv & 1;
    const int wn   = wv >> 1;

    const int scol = (((lane & 3) ^ ((lane >> 3) & 3))) * 8;

    const int ar0 = wv * 16 + (lane >> 2);
    const int ar1 = 64 + ar0;
    const int i0 = m0 + ar0, i1 = m0 + ar1;
    const size_t hr0 = (size_t)(off + (i0 < cnt ? i0 : cnt - 1)) * H_DIM;
    const size_t hr1 = (size_t)(off + (i1 < cnt ? i1 : cnt - 1)) * H_DIM;
    const bf16* ga0 = h + hr0 + scol;
    const bf16* ga1 = h + hr1 + scol;
    const bf16* gb0 = w2b + ((size_t)e * C_DIM + n0 + ar0) * H_DIM + scol;
    const bf16* gb1 = w2b + ((size_t)e * C_DIM + n0 + ar1) * H_DIM + scol;

    f32x4 acc[4][4];
#pragma unroll
    for (int mi = 0; mi < 4; ++mi)
#pragma unroll
        for (int ni = 0; ni < 4; ++ni)
#pragma unroll
            for (int r = 0; r < 4; ++r) acc[mi][ni][r] = 0.f;

    const int r_   = lane & 15;
    const int g_   = lane >> 4;
    const int rcol = (g_ ^ ((r_ >> 1) & 3)) * 8;

#define STAGE2(b, kt) do { const int k0_ = (kt) * 32;        \
    async_ld16(ga0 + k0_, &As[b][wv * 16][0]);               \
    async_ld16(ga1 + k0_, &As[b][64 + wv * 16][0]);          \
    async_ld16(gb0 + k0_, &Bs[b][wv * 16][0]);               \
    async_ld16(gb1 + k0_, &Bs[b][64 + wv * 16][0]); } while (0)

    STAGE2(0, 0);
    __syncthreads();
    int cur = 0;
    for (int kt = 0; kt < H_DIM / 32; ++kt) {
        if (kt + 1 < H_DIM / 32) STAGE2(cur ^ 1, kt + 1);

        bf16x8 af[4];
#pragma unroll
        for (int mi = 0; mi < 4; ++mi)
            af[mi] = *(const bf16x8*)&As[cur][wm * 64 + mi * 16 + r_][rcol];
#pragma unroll
        for (int ni = 0; ni < 4; ++ni) {
            bf16x8 bfr = *(const bf16x8*)&Bs[cur][wn * 64 + ni * 16 + r_][rcol];
#pragma unroll
            for (int mi = 0; mi < 4; ++mi)
                acc[mi][ni] = __builtin_amdgcn_mfma_f32_16x16x32_bf16(af[mi], bfr, acc[mi][ni], 0, 0, 0);
        }
        __syncthreads();
        cur ^= 1;
    }
#undef STAGE2

    const int lg = lane >> 4, ln = lane & 15;
#pragma unroll
    for (int mi = 0; mi < 4; ++mi) {
#pragma unroll
        for (int r = 0; r < 4; ++r) {
            const int m = wm * 64 + mi * 16 + lg * 4 + r;
            if (m0 + m < cnt) {
                const int   tk = tok[e * CAP + m0 + m];
                const float g  = gate[e * CAP + m0 + m];
#pragma unroll
                for (int ni = 0; ni < 4; ++ni) {
                    const int n = n0 + wn * 64 + ni * 16 + ln;
                    float v = (acc[mi][ni][r] + b2[(size_t)e * C_DIM + n]) * g;
                    atomicAdd(&out[(size_t)tk * C_DIM + n], v);
                }
            }
        }
    }
}

extern "C" void kernel_launch(void* const* d_in, const int* in_sizes, int n_in,
                              void* d_out, int out_size, void* d_ws, size_t ws_size,
                              hipStream_t stream) {
    const float* x  = (const float*)d_in[0];
    const float* rw = (const float*)d_in[1];
    const float* w1 = (const float*)d_in[2];
    const float* b1 = (const float*)d_in[3];
    const float* w2 = (const float*)d_in[4];
    const float* b2 = (const float*)d_in[5];
    float* out = (float*)d_out;

    // ws layout (~280 MiB)
    char* ws = (char*)d_ws;
    size_t o = 0;
    bf16* xb     = (bf16*)(ws + o);  o += (size_t)N_TOK * C_DIM * sizeof(bf16);        // 16 MiB
    bf16* w1b    = (bf16*)(ws + o);  o += (size_t)N_EXP * H_DIM * C_DIM * sizeof(bf16); // 64 MiB
    bf16* w2b    = (bf16*)(ws + o);  o += (size_t)N_EXP * C_DIM * H_DIM * sizeof(bf16); // 64 MiB
    int*  tok    = (int*)(ws + o);   o += (size_t)N_EXP * CAP * sizeof(int);           // 256 KiB
    float* gate  = (float*)(ws + o); o += (size_t)N_EXP * CAP * sizeof(float);         // 256 KiB
    int*  counts = (int*)(ws + o);   o += 128;
    bf16* h      = (bf16*)(ws + o);  o += (size_t)(2 * N_TOK) * H_DIM * sizeof(bf16);  // 128 MiB

    hipMemsetAsync(d_out, 0, (size_t)N_TOK * C_DIM * sizeof(float), stream);
    hipMemsetAsync(counts, 0, 128, stream);

    cvt_all_k<<<dim3((unsigned)((NCVT + 255) / 256)), dim3(256), 0, stream>>>(x, w1, w2, xb, w1b, w2b);
    router_k<<<dim3(N_TOK / 16), dim3(1024), 0, stream>>>(x, rw, counts, tok, gate);
    fc1_k<<<dim3(32, 64, N_EXP), dim3(256), 0, stream>>>(xb, w1b, b1, counts, tok, h);
    fc2_k<<<dim3(8, 64, N_EXP), dim3(256), 0, stream>>>(h, w2b, b2, counts, tok, gate, out);
}